// Round 3
// baseline (20.658 us; speedup 1.0000x reference)
//
#include <hip/hip_runtime.h>

// out[b,p] = sum_s (x[b,s,3] - x[b,S-1,3]) * W[3,p,s] + bias[3,p] + x[b,S-1,3]
// Only channel c=3 survives the reference's final slice.

constexpr int B = 1024, S = 336, C = 321, P = 96;
constexpr int BPB   = 4;    // batches per block
constexpr int BLOCK = 256;  // 4 waves

__global__ __launch_bounds__(BLOCK) void nlinear_c3_kernel(
    const float* __restrict__ x, const float* __restrict__ W,
    const float* __restrict__ bias, float* __restrict__ out)
{
    __shared__ float xs[BPB][S];   // 4*336*4B = 5.25 KB

    const int b0 = blockIdx.x * BPB;

    // Phase 1: gather x[b, :, 3] for BPB batches into LDS (strided HBM reads).
    for (int idx = threadIdx.x; idx < BPB * S; idx += BLOCK) {
        const int bi = idx / S;
        const int s  = idx - bi * S;
        xs[bi][s] = x[((size_t)(b0 + bi) * S + s) * C + 3];
    }
    __syncthreads();

    // Phase 2: thread p computes outputs for 2 batches; two 128-thread groups
    // cover the 4 batches (W row re-read by the 2nd group hits L1/L2).
    const int g = threadIdx.x >> 7;   // 0 or 1
    const int p = threadIdx.x & 127;
    if (p < P) {
        const int bA = 2 * g, bB = 2 * g + 1;
        const float lastA = xs[bA][S - 1];
        const float lastB = xs[bB][S - 1];

        const float4* __restrict__ wp4 =
            reinterpret_cast<const float4*>(W + (size_t)(3 * P + p) * S);  // 1344B rows, 16B aligned
        const float4* xA4 = reinterpret_cast<const float4*>(xs[bA]);
        const float4* xB4 = reinterpret_cast<const float4*>(xs[bB]);

        float accA = 0.f, accB = 0.f, sw = 0.f;
        #pragma unroll 4
        for (int i = 0; i < S / 4; ++i) {   // 336/4 = 84
            const float4 w  = wp4[i];
            const float4 a  = xA4[i];
            const float4 c  = xB4[i];
            accA += a.x * w.x + a.y * w.y + a.z * w.z + a.w * w.w;
            accB += c.x * w.x + c.y * w.y + c.z * w.z + c.w * w.w;
            sw   += w.x + w.y + w.z + w.w;
        }

        const float bb = bias[3 * P + p];
        // (x - last)·w  ==  x·w - last*Σw ; then + bias + last
        out[(size_t)(b0 + bA) * P + p] = accA - lastA * sw + bb + lastA;
        out[(size_t)(b0 + bB) * P + p] = accB - lastB * sw + bb + lastB;
    }
}

extern "C" void kernel_launch(void* const* d_in, const int* in_sizes, int n_in,
                              void* d_out, int out_size, void* d_ws, size_t ws_size,
                              hipStream_t stream) {
    const float* x    = (const float*)d_in[0];
    const float* W    = (const float*)d_in[1];
    const float* bias = (const float*)d_in[2];
    float* out        = (float*)d_out;

    nlinear_c3_kernel<<<B / BPB, BLOCK, 0, stream>>>(x, W, bias, out);
}